// Round 1
// baseline (229.816 us; speedup 1.0000x reference)
//
#include <hip/hip_runtime.h>
#include <float.h>

// PointGroup: per-cluster voxelize + mean-per-voxel + max-pool + linear score.
// Exploits: pooled[c] = max over NON-EMPTY voxels of (featsum/cnt); empty
// voxels are never gathered by points, so no vfeat materialization needed.
// One block per cluster (clusters contiguous via clusters_offset).

constexpr int kC    = 32;
constexpr int kFS   = 14;
constexpr int kNVOX = kFS * kFS * kFS;  // 2744
constexpr int kBLK  = 256;
constexpr int kCH   = 4;                // channels per LDS chunk
constexpr int kPPT  = 8;                // points per thread (2048/256)

__device__ inline float wsum(float v) {
#pragma unroll
  for (int o = 32; o; o >>= 1) v += __shfl_down(v, o);
  return v;
}
__device__ inline float wmin(float v) {
#pragma unroll
  for (int o = 32; o; o >>= 1) v = fminf(v, __shfl_down(v, o));
  return v;
}
__device__ inline float wmax(float v) {
#pragma unroll
  for (int o = 32; o; o >>= 1) v = fmaxf(v, __shfl_down(v, o));
  return v;
}

__global__ __launch_bounds__(kBLK) void pg_kernel(
    const float* __restrict__ feats, const float* __restrict__ coords,
    const float* __restrict__ W, const float* __restrict__ bias,
    const float* __restrict__ rand3, const int* __restrict__ cidx,
    const int* __restrict__ coff, float* __restrict__ out) {
  __shared__ float s_cnt[kNVOX];
  __shared__ float s_feat[kNVOX * kCH];   // 43904 B
  __shared__ float s_red[4 * 9];
  __shared__ float s_bcast[7];
  __shared__ float s_pool[kC];

  const int c = blockIdx.x;
  const int tid = threadIdx.x;
  const int lane = tid & 63, wave = tid >> 6;
  const int start = coff[c], end = coff[c + 1];

  // ---- Phase A: gather coords, reduce sum/min/max ----
  int pt[kPPT];
  float px[kPPT], py[kPPT], pz[kPPT];
  float sx = 0.f, sy = 0.f, sz = 0.f;
  float mnx = FLT_MAX, mny = FLT_MAX, mnz = FLT_MAX;
  float mxx = -FLT_MAX, mxy = -FLT_MAX, mxz = -FLT_MAX;
#pragma unroll
  for (int k = 0; k < kPPT; k++) {
    int i = start + tid + k * kBLK;
    if (i < end) {
      int p = cidx[2 * i + 1];
      pt[k] = p;
      float x = coords[3 * p + 0], y = coords[3 * p + 1], z = coords[3 * p + 2];
      px[k] = x; py[k] = y; pz[k] = z;
      sx += x; sy += y; sz += z;
      mnx = fminf(mnx, x); mny = fminf(mny, y); mnz = fminf(mnz, z);
      mxx = fmaxf(mxx, x); mxy = fmaxf(mxy, y); mxz = fmaxf(mxz, z);
    } else {
      pt[k] = -1;
    }
  }
  sx = wsum(sx); sy = wsum(sy); sz = wsum(sz);
  mnx = wmin(mnx); mny = wmin(mny); mnz = wmin(mnz);
  mxx = wmax(mxx); mxy = wmax(mxy); mxz = wmax(mxz);
  if (lane == 0) {
    float* r = &s_red[wave * 9];
    r[0] = sx; r[1] = sy; r[2] = sz;
    r[3] = mnx; r[4] = mny; r[5] = mnz;
    r[6] = mxx; r[7] = mxy; r[8] = mxz;
  }
  __syncthreads();
  if (tid == 0) {
    float Sx = s_red[0], Sy = s_red[1], Sz = s_red[2];
    float Mnx = s_red[3], Mny = s_red[4], Mnz = s_red[5];
    float Mxx = s_red[6], Mxy = s_red[7], Mxz = s_red[8];
    for (int w = 1; w < kBLK / 64; w++) {
      const float* r = &s_red[w * 9];
      Sx += r[0]; Sy += r[1]; Sz += r[2];
      Mnx = fminf(Mnx, r[3]); Mny = fminf(Mny, r[4]); Mnz = fminf(Mnz, r[5]);
      Mxx = fmaxf(Mxx, r[6]); Mxy = fmaxf(Mxy, r[7]); Mxz = fmaxf(Mxz, r[8]);
    }
    float n = (float)(end - start);
    float cmx = Sx / n, cmy = Sy / n, cmz = Sz / n;
    // centered min/max (subtraction is monotonic, so min/max commute)
    float cminx = Mnx - cmx, cminy = Mny - cmy, cminz = Mnz - cmz;
    float cmaxx = Mxx - cmx, cmaxy = Mxy - cmy, cmaxz = Mxz - cmz;
    float r0 = (cmaxx - cminx) / 14.0f;
    float r1 = (cmaxy - cminy) / 14.0f;
    float r2 = (cmaxz - cminz) / 14.0f;
    float cs = 1.0f / fmaxf(fmaxf(r0, r1), r2) - 0.01f;
    cs = fminf(cs, 50.0f);
    float r3x = rand3[0], r3y = rand3[1], r3z = rand3[2];
    float mn0 = cminx * cs, mx0 = cmaxx * cs, b0 = mx0 - mn0;
    float mn1 = cminy * cs, mx1 = cmaxy * cs, b1 = mx1 - mn1;
    float mn2 = cminz * cs, mx2 = cmaxz * cs, b2 = mx2 - mn2;
    float ox = -mn0 + fmaxf(14.0f - b0 - 0.001f, 0.0f) * r3x +
               fminf(14.0f - b0 + 0.001f, 0.0f) * r3x;
    float oy = -mn1 + fmaxf(14.0f - b1 - 0.001f, 0.0f) * r3y +
               fminf(14.0f - b1 + 0.001f, 0.0f) * r3y;
    float oz = -mn2 + fmaxf(14.0f - b2 - 0.001f, 0.0f) * r3z +
               fminf(14.0f - b2 + 0.001f, 0.0f) * r3z;
    s_bcast[0] = cmx; s_bcast[1] = cmy; s_bcast[2] = cmz;
    s_bcast[3] = cs;
    s_bcast[4] = ox; s_bcast[5] = oy; s_bcast[6] = oz;
  }
  __syncthreads();
  const float cmx = s_bcast[0], cmy = s_bcast[1], cmz = s_bcast[2];
  const float cs = s_bcast[3];
  const float ox = s_bcast[4], oy = s_bcast[5], oz = s_bcast[6];

  // ---- voxel ids (reference FP op order: (c - mean) * scale + off) ----
  int vid[kPPT];
#pragma unroll
  for (int k = 0; k < kPPT; k++) {
    if (pt[k] >= 0) {
      float tx = (px[k] - cmx) * cs + ox;
      float ty = (py[k] - cmy) * cs + oy;
      float tz = (pz[k] - cmz) * cs + oz;
      int vx = min(kFS - 1, max(0, (int)floorf(tx)));
      int vy = min(kFS - 1, max(0, (int)floorf(ty)));
      int vz = min(kFS - 1, max(0, (int)floorf(tz)));
      vid[k] = (vx * kFS + vy) * kFS + vz;
    } else {
      vid[k] = -1;
    }
  }

  // ---- voxel counts ----
  for (int v = tid; v < kNVOX; v += kBLK) s_cnt[v] = 0.0f;
  __syncthreads();
#pragma unroll
  for (int k = 0; k < kPPT; k++)
    if (vid[k] >= 0) atomicAdd(&s_cnt[vid[k]], 1.0f);
  __syncthreads();

  // ---- per-chunk feature sums + max-of-means ----
  for (int ch0 = 0; ch0 < kC; ch0 += kCH) {
    for (int v = tid; v < kNVOX * kCH; v += kBLK) s_feat[v] = 0.0f;
    __syncthreads();
#pragma unroll
    for (int k = 0; k < kPPT; k++) {
      if (vid[k] >= 0) {
        const float4 f =
            *reinterpret_cast<const float4*>(&feats[(size_t)pt[k] * kC + ch0]);
        float* dst = &s_feat[vid[k] * kCH];
        atomicAdd(dst + 0, f.x);
        atomicAdd(dst + 1, f.y);
        atomicAdd(dst + 2, f.z);
        atomicAdd(dst + 3, f.w);
      }
    }
    __syncthreads();
    float m0 = -FLT_MAX, m1 = -FLT_MAX, m2 = -FLT_MAX, m3 = -FLT_MAX;
    for (int v = tid; v < kNVOX; v += kBLK) {
      float ct = s_cnt[v];
      if (ct > 0.0f) {
        const float* src = &s_feat[v * kCH];
        m0 = fmaxf(m0, src[0] / ct);
        m1 = fmaxf(m1, src[1] / ct);
        m2 = fmaxf(m2, src[2] / ct);
        m3 = fmaxf(m3, src[3] / ct);
      }
    }
    m0 = wmax(m0); m1 = wmax(m1); m2 = wmax(m2); m3 = wmax(m3);
    if (lane == 0) {
      float* r = &s_red[wave * kCH];
      r[0] = m0; r[1] = m1; r[2] = m2; r[3] = m3;
    }
    __syncthreads();
    if (tid < kCH) {
      float mm = s_red[tid];
      for (int w = 1; w < kBLK / 64; w++) mm = fmaxf(mm, s_red[w * kCH + tid]);
      s_pool[ch0 + tid] = mm;
    }
    __syncthreads();
  }

  // ---- score ----
  if (tid == 0) {
    float acc = bias[0];
    for (int j = 0; j < kC; j++) acc += s_pool[j] * W[j];
    out[c] = acc;
  }
}

extern "C" void kernel_launch(void* const* d_in, const int* in_sizes, int n_in,
                              void* d_out, int out_size, void* d_ws,
                              size_t ws_size, hipStream_t stream) {
  const float* feats  = (const float*)d_in[0];
  const float* coords = (const float*)d_in[1];
  const float* W      = (const float*)d_in[2];
  const float* bias   = (const float*)d_in[3];
  const float* rand3  = (const float*)d_in[4];
  const int* cidx     = (const int*)d_in[5];
  const int* coff     = (const int*)d_in[6];
  float* out          = (float*)d_out;

  int nC = in_sizes[6] - 1;  // clusters_offset has NC+1 entries
  pg_kernel<<<nC, kBLK, 0, stream>>>(feats, coords, W, bias, rand3, cidx, coff,
                                     out);
}

// Round 2
// 77.984 us; speedup vs baseline: 2.9470x; 2.9470x over previous
//
#include <hip/hip_runtime.h>
#include <float.h>

// PointGroup: per-cluster voxelize + mean-per-voxel + max-pool + linear score.
// R2: counting-sort points by voxel id in LDS, then gather each point's full
// 32-ch feats row EXACTLY ONCE (8x float4, both 64B lines used) and accumulate
// per-voxel mean in registers. Removes the 8 channel-chunk phases and the 33M
// LDS float atomics of R1, and cuts HBM fetch ~4x.

constexpr int kC    = 32;
constexpr int kFS   = 14;
constexpr int kNVOX = kFS * kFS * kFS;  // 2744
constexpr int kBLK  = 256;
constexpr int kPPT  = 8;                // points per thread (2048/256)
constexpr int kPTS  = 2048;             // points per cluster
constexpr int kCPT  = (kNVOX + kBLK - 1) / kBLK;  // 11 voxels per thread

__device__ inline float wsum(float v) {
#pragma unroll
  for (int o = 32; o; o >>= 1) v += __shfl_down(v, o);
  return v;
}
__device__ inline float wmin(float v) {
#pragma unroll
  for (int o = 32; o; o >>= 1) v = fminf(v, __shfl_down(v, o));
  return v;
}
__device__ inline float wmax(float v) {
#pragma unroll
  for (int o = 32; o; o >>= 1) v = fmaxf(v, __shfl_down(v, o));
  return v;
}

__global__ __launch_bounds__(kBLK) void pg_kernel(
    const float* __restrict__ feats, const float* __restrict__ coords,
    const float* __restrict__ W, const float* __restrict__ bias,
    const float* __restrict__ rand3, const int* __restrict__ cidx,
    const int* __restrict__ coff, float* __restrict__ out) {
  __shared__ int s_cnt[kNVOX];     // 10976 B: per-voxel count
  __shared__ int s_off[kNVOX];     // 10976 B: exclusive start -> end after scatter
  __shared__ int s_sorted[kPTS];   //  8192 B: point ids sorted by voxel
  __shared__ float s_red[4 * 9];
  __shared__ float s_redmax[4 * kC];
  __shared__ float s_bcast[7];
  __shared__ int s_wt[kBLK / 64];

  const int c = blockIdx.x;
  const int tid = threadIdx.x;
  const int lane = tid & 63, wave = tid >> 6;
  const int start = coff[c], end = coff[c + 1];

  // ---- Phase A: gather coords, reduce sum/min/max ----
  int pt[kPPT];
  float px[kPPT], py[kPPT], pz[kPPT];
  float sx = 0.f, sy = 0.f, sz = 0.f;
  float mnx = FLT_MAX, mny = FLT_MAX, mnz = FLT_MAX;
  float mxx = -FLT_MAX, mxy = -FLT_MAX, mxz = -FLT_MAX;
#pragma unroll
  for (int k = 0; k < kPPT; k++) {
    int i = start + tid + k * kBLK;
    if (i < end) {
      int p = cidx[2 * i + 1];
      pt[k] = p;
      float x = coords[3 * p + 0], y = coords[3 * p + 1], z = coords[3 * p + 2];
      px[k] = x; py[k] = y; pz[k] = z;
      sx += x; sy += y; sz += z;
      mnx = fminf(mnx, x); mny = fminf(mny, y); mnz = fminf(mnz, z);
      mxx = fmaxf(mxx, x); mxy = fmaxf(mxy, y); mxz = fmaxf(mxz, z);
    } else {
      pt[k] = -1;
    }
  }
  sx = wsum(sx); sy = wsum(sy); sz = wsum(sz);
  mnx = wmin(mnx); mny = wmin(mny); mnz = wmin(mnz);
  mxx = wmax(mxx); mxy = wmax(mxy); mxz = wmax(mxz);
  if (lane == 0) {
    float* r = &s_red[wave * 9];
    r[0] = sx; r[1] = sy; r[2] = sz;
    r[3] = mnx; r[4] = mny; r[5] = mnz;
    r[6] = mxx; r[7] = mxy; r[8] = mxz;
  }
  __syncthreads();
  if (tid == 0) {
    float Sx = s_red[0], Sy = s_red[1], Sz = s_red[2];
    float Mnx = s_red[3], Mny = s_red[4], Mnz = s_red[5];
    float Mxx = s_red[6], Mxy = s_red[7], Mxz = s_red[8];
    for (int w = 1; w < kBLK / 64; w++) {
      const float* r = &s_red[w * 9];
      Sx += r[0]; Sy += r[1]; Sz += r[2];
      Mnx = fminf(Mnx, r[3]); Mny = fminf(Mny, r[4]); Mnz = fminf(Mnz, r[5]);
      Mxx = fmaxf(Mxx, r[6]); Mxy = fmaxf(Mxy, r[7]); Mxz = fmaxf(Mxz, r[8]);
    }
    float n = (float)(end - start);
    float cmx = Sx / n, cmy = Sy / n, cmz = Sz / n;
    float cminx = Mnx - cmx, cminy = Mny - cmy, cminz = Mnz - cmz;
    float cmaxx = Mxx - cmx, cmaxy = Mxy - cmy, cmaxz = Mxz - cmz;
    float r0 = (cmaxx - cminx) / 14.0f;
    float r1 = (cmaxy - cminy) / 14.0f;
    float r2 = (cmaxz - cminz) / 14.0f;
    float cs = 1.0f / fmaxf(fmaxf(r0, r1), r2) - 0.01f;
    cs = fminf(cs, 50.0f);
    float r3x = rand3[0], r3y = rand3[1], r3z = rand3[2];
    float mn0 = cminx * cs, mx0 = cmaxx * cs, b0 = mx0 - mn0;
    float mn1 = cminy * cs, mx1 = cmaxy * cs, b1 = mx1 - mn1;
    float mn2 = cminz * cs, mx2 = cmaxz * cs, b2 = mx2 - mn2;
    float ox = -mn0 + fmaxf(14.0f - b0 - 0.001f, 0.0f) * r3x +
               fminf(14.0f - b0 + 0.001f, 0.0f) * r3x;
    float oy = -mn1 + fmaxf(14.0f - b1 - 0.001f, 0.0f) * r3y +
               fminf(14.0f - b1 + 0.001f, 0.0f) * r3y;
    float oz = -mn2 + fmaxf(14.0f - b2 - 0.001f, 0.0f) * r3z +
               fminf(14.0f - b2 + 0.001f, 0.0f) * r3z;
    s_bcast[0] = cmx; s_bcast[1] = cmy; s_bcast[2] = cmz;
    s_bcast[3] = cs;
    s_bcast[4] = ox; s_bcast[5] = oy; s_bcast[6] = oz;
  }
  __syncthreads();
  const float cmx = s_bcast[0], cmy = s_bcast[1], cmz = s_bcast[2];
  const float cs = s_bcast[3];
  const float ox = s_bcast[4], oy = s_bcast[5], oz = s_bcast[6];

  // ---- voxel ids (reference FP op order: (c - mean) * scale + off) ----
  int vid[kPPT];
#pragma unroll
  for (int k = 0; k < kPPT; k++) {
    if (pt[k] >= 0) {
      float tx = (px[k] - cmx) * cs + ox;
      float ty = (py[k] - cmy) * cs + oy;
      float tz = (pz[k] - cmz) * cs + oz;
      int vx = min(kFS - 1, max(0, (int)floorf(tx)));
      int vy = min(kFS - 1, max(0, (int)floorf(ty)));
      int vz = min(kFS - 1, max(0, (int)floorf(tz)));
      vid[k] = (vx * kFS + vy) * kFS + vz;
    } else {
      vid[k] = -1;
    }
  }

  // ---- counting sort: counts ----
  for (int v = tid; v < kNVOX; v += kBLK) s_cnt[v] = 0;
  __syncthreads();
#pragma unroll
  for (int k = 0; k < kPPT; k++)
    if (vid[k] >= 0) atomicAdd(&s_cnt[vid[k]], 1);
  __syncthreads();

  // ---- exclusive prefix scan over s_cnt -> s_off ----
  {
    const int base = tid * kCPT;
    int local[kCPT];
    int sum = 0;
#pragma unroll
    for (int j = 0; j < kCPT; j++) {
      int v = base + j;
      int x = (v < kNVOX) ? s_cnt[v] : 0;
      local[j] = sum;       // exclusive within chunk
      sum += x;
    }
    // wave inclusive scan of per-thread sums
    int inc = sum;
#pragma unroll
    for (int o = 1; o < 64; o <<= 1) {
      int t = __shfl_up(inc, o);
      if (lane >= o) inc += t;
    }
    if (lane == 63) s_wt[wave] = inc;
    __syncthreads();
    if (tid == 0) {
      int a = 0;
      for (int w = 0; w < kBLK / 64; w++) {
        int t = s_wt[w];
        s_wt[w] = a;
        a += t;
      }
    }
    __syncthreads();
    const int texcl = s_wt[wave] + inc - sum;  // exclusive prefix for thread
#pragma unroll
    for (int j = 0; j < kCPT; j++) {
      int v = base + j;
      if (v < kNVOX) s_off[v] = texcl + local[j];
    }
  }
  __syncthreads();

  // ---- scatter (s_off becomes per-voxel END after this) ----
#pragma unroll
  for (int k = 0; k < kPPT; k++) {
    if (vid[k] >= 0) {
      int pos = atomicAdd(&s_off[vid[k]], 1);
      s_sorted[pos] = pt[k];
    }
  }
  __syncthreads();

  // ---- per-voxel: gather full rows once, mean, running max ----
  float mx[kC];
#pragma unroll
  for (int ch = 0; ch < kC; ch++) mx[ch] = -FLT_MAX;

  for (int i = 0; i < kCPT; i++) {
    int v = tid + i * kBLK;
    if (v >= kNVOX) break;
    int cn = s_cnt[v];
    if (cn == 0) continue;
    int e = s_off[v];
    int b = e - cn;
    float acc[kC];
#pragma unroll
    for (int ch = 0; ch < kC; ch++) acc[ch] = 0.0f;
    for (int j = b; j < e; j++) {
      int p = s_sorted[j];
      const float* rowp = &feats[(size_t)p * kC];
#pragma unroll
      for (int q = 0; q < kC / 4; q++) {
        float4 f = *reinterpret_cast<const float4*>(rowp + 4 * q);
        acc[4 * q + 0] += f.x;
        acc[4 * q + 1] += f.y;
        acc[4 * q + 2] += f.z;
        acc[4 * q + 3] += f.w;
      }
    }
    float fc = (float)cn;
#pragma unroll
    for (int ch = 0; ch < kC; ch++) mx[ch] = fmaxf(mx[ch], acc[ch] / fc);
  }

  // ---- block-reduce mx[32] ----
#pragma unroll
  for (int ch = 0; ch < kC; ch++) mx[ch] = wmax(mx[ch]);
  if (lane == 0) {
#pragma unroll
    for (int ch = 0; ch < kC; ch++) s_redmax[wave * kC + ch] = mx[ch];
  }
  __syncthreads();
  if (tid < kC) {
    float mm = s_redmax[tid];
    for (int w = 1; w < kBLK / 64; w++)
      mm = fmaxf(mm, s_redmax[w * kC + tid]);
    s_redmax[tid] = mm;
  }
  __syncthreads();

  // ---- score ----
  if (tid == 0) {
    float acc = bias[0];
    for (int j = 0; j < kC; j++) acc += s_redmax[j] * W[j];
    out[c] = acc;
  }
}

extern "C" void kernel_launch(void* const* d_in, const int* in_sizes, int n_in,
                              void* d_out, int out_size, void* d_ws,
                              size_t ws_size, hipStream_t stream) {
  const float* feats  = (const float*)d_in[0];
  const float* coords = (const float*)d_in[1];
  const float* W      = (const float*)d_in[2];
  const float* bias   = (const float*)d_in[3];
  const float* rand3  = (const float*)d_in[4];
  const int* cidx     = (const int*)d_in[5];
  const int* coff     = (const int*)d_in[6];
  float* out          = (float*)d_out;

  int nC = in_sizes[6] - 1;  // clusters_offset has NC+1 entries
  pg_kernel<<<nC, kBLK, 0, stream>>>(feats, coords, W, bias, rand3, cidx, coff,
                                     out);
}

// Round 3
// 56.427 us; speedup vs baseline: 4.0728x; 1.3820x over previous
//
#include <hip/hip_runtime.h>
#include <float.h>

// PointGroup R3: block=1024 (16 waves -> 32 waves/CU at 2 blocks/CU) and
// 8-lanes-per-voxel channel-split gather: each point's 128B feats row is one
// coalesced read by 8 consecutive lanes; per-group load variance is much lower
// than per-lane. Counting-sort structure from R2 unchanged.

constexpr int kC    = 32;
constexpr int kFS   = 14;
constexpr int kNVOX = kFS * kFS * kFS;  // 2744
constexpr int kBLK  = 1024;
constexpr int kW    = kBLK / 64;        // 16 waves
constexpr int kPPT  = 2;                // points per thread (2048/1024)
constexpr int kPTS  = 2048;
constexpr int kCPT  = (kNVOX + kBLK - 1) / kBLK;  // 3 voxels per thread (scan)
constexpr int kGRP  = kBLK / 8;         // 128 voxel-groups

__device__ inline float wsum(float v) {
#pragma unroll
  for (int o = 32; o; o >>= 1) v += __shfl_down(v, o);
  return v;
}
__device__ inline float wmin(float v) {
#pragma unroll
  for (int o = 32; o; o >>= 1) v = fminf(v, __shfl_down(v, o));
  return v;
}
__device__ inline float wmax(float v) {
#pragma unroll
  for (int o = 32; o; o >>= 1) v = fmaxf(v, __shfl_down(v, o));
  return v;
}

__global__ __launch_bounds__(kBLK) void pg_kernel(
    const float* __restrict__ feats, const float* __restrict__ coords,
    const float* __restrict__ W, const float* __restrict__ bias,
    const float* __restrict__ rand3, const int* __restrict__ cidx,
    const int* __restrict__ coff, float* __restrict__ out) {
  __shared__ int s_cnt[kNVOX];
  __shared__ int s_off[kNVOX];
  __shared__ int s_sorted[kPTS];
  __shared__ float s_red[kW * 9];
  __shared__ float s_redmax[kW * kC];
  __shared__ float s_bcast[7];
  __shared__ int s_wt[kW];

  const int c = blockIdx.x;
  const int tid = threadIdx.x;
  const int lane = tid & 63, wave = tid >> 6;
  const int start = coff[c], end = coff[c + 1];

  // ---- Phase A: gather coords, reduce sum/min/max ----
  int pt[kPPT];
  float px[kPPT], py[kPPT], pz[kPPT];
  float sx = 0.f, sy = 0.f, sz = 0.f;
  float mnx = FLT_MAX, mny = FLT_MAX, mnz = FLT_MAX;
  float mxx = -FLT_MAX, mxy = -FLT_MAX, mxz = -FLT_MAX;
#pragma unroll
  for (int k = 0; k < kPPT; k++) {
    int i = start + tid + k * kBLK;
    if (i < end) {
      int p = cidx[2 * i + 1];
      pt[k] = p;
      float x = coords[3 * p + 0], y = coords[3 * p + 1], z = coords[3 * p + 2];
      px[k] = x; py[k] = y; pz[k] = z;
      sx += x; sy += y; sz += z;
      mnx = fminf(mnx, x); mny = fminf(mny, y); mnz = fminf(mnz, z);
      mxx = fmaxf(mxx, x); mxy = fmaxf(mxy, y); mxz = fmaxf(mxz, z);
    } else {
      pt[k] = -1;
    }
  }
  sx = wsum(sx); sy = wsum(sy); sz = wsum(sz);
  mnx = wmin(mnx); mny = wmin(mny); mnz = wmin(mnz);
  mxx = wmax(mxx); mxy = wmax(mxy); mxz = wmax(mxz);
  if (lane == 0) {
    float* r = &s_red[wave * 9];
    r[0] = sx; r[1] = sy; r[2] = sz;
    r[3] = mnx; r[4] = mny; r[5] = mnz;
    r[6] = mxx; r[7] = mxy; r[8] = mxz;
  }
  __syncthreads();
  if (tid == 0) {
    float Sx = s_red[0], Sy = s_red[1], Sz = s_red[2];
    float Mnx = s_red[3], Mny = s_red[4], Mnz = s_red[5];
    float Mxx = s_red[6], Mxy = s_red[7], Mxz = s_red[8];
    for (int w = 1; w < kW; w++) {
      const float* r = &s_red[w * 9];
      Sx += r[0]; Sy += r[1]; Sz += r[2];
      Mnx = fminf(Mnx, r[3]); Mny = fminf(Mny, r[4]); Mnz = fminf(Mnz, r[5]);
      Mxx = fmaxf(Mxx, r[6]); Mxy = fmaxf(Mxy, r[7]); Mxz = fmaxf(Mxz, r[8]);
    }
    float n = (float)(end - start);
    float cmx = Sx / n, cmy = Sy / n, cmz = Sz / n;
    float cminx = Mnx - cmx, cminy = Mny - cmy, cminz = Mnz - cmz;
    float cmaxx = Mxx - cmx, cmaxy = Mxy - cmy, cmaxz = Mxz - cmz;
    float r0 = (cmaxx - cminx) / 14.0f;
    float r1 = (cmaxy - cminy) / 14.0f;
    float r2 = (cmaxz - cminz) / 14.0f;
    float cs = 1.0f / fmaxf(fmaxf(r0, r1), r2) - 0.01f;
    cs = fminf(cs, 50.0f);
    float r3x = rand3[0], r3y = rand3[1], r3z = rand3[2];
    float mn0 = cminx * cs, mx0 = cmaxx * cs, b0 = mx0 - mn0;
    float mn1 = cminy * cs, mx1 = cmaxy * cs, b1 = mx1 - mn1;
    float mn2 = cminz * cs, mx2 = cmaxz * cs, b2 = mx2 - mn2;
    float ox = -mn0 + fmaxf(14.0f - b0 - 0.001f, 0.0f) * r3x +
               fminf(14.0f - b0 + 0.001f, 0.0f) * r3x;
    float oy = -mn1 + fmaxf(14.0f - b1 - 0.001f, 0.0f) * r3y +
               fminf(14.0f - b1 + 0.001f, 0.0f) * r3y;
    float oz = -mn2 + fmaxf(14.0f - b2 - 0.001f, 0.0f) * r3z +
               fminf(14.0f - b2 + 0.001f, 0.0f) * r3z;
    s_bcast[0] = cmx; s_bcast[1] = cmy; s_bcast[2] = cmz;
    s_bcast[3] = cs;
    s_bcast[4] = ox; s_bcast[5] = oy; s_bcast[6] = oz;
  }
  __syncthreads();
  const float cmx = s_bcast[0], cmy = s_bcast[1], cmz = s_bcast[2];
  const float cs = s_bcast[3];
  const float ox = s_bcast[4], oy = s_bcast[5], oz = s_bcast[6];

  // ---- voxel ids (reference FP op order) ----
  int vid[kPPT];
#pragma unroll
  for (int k = 0; k < kPPT; k++) {
    if (pt[k] >= 0) {
      float tx = (px[k] - cmx) * cs + ox;
      float ty = (py[k] - cmy) * cs + oy;
      float tz = (pz[k] - cmz) * cs + oz;
      int vx = min(kFS - 1, max(0, (int)floorf(tx)));
      int vy = min(kFS - 1, max(0, (int)floorf(ty)));
      int vz = min(kFS - 1, max(0, (int)floorf(tz)));
      vid[k] = (vx * kFS + vy) * kFS + vz;
    } else {
      vid[k] = -1;
    }
  }

  // ---- counting sort: counts ----
  for (int v = tid; v < kNVOX; v += kBLK) s_cnt[v] = 0;
  __syncthreads();
#pragma unroll
  for (int k = 0; k < kPPT; k++)
    if (vid[k] >= 0) atomicAdd(&s_cnt[vid[k]], 1);
  __syncthreads();

  // ---- exclusive prefix scan over s_cnt -> s_off ----
  {
    const int base = tid * kCPT;
    int local[kCPT];
    int sum = 0;
#pragma unroll
    for (int j = 0; j < kCPT; j++) {
      int v = base + j;
      int x = (v < kNVOX) ? s_cnt[v] : 0;
      local[j] = sum;
      sum += x;
    }
    int inc = sum;
#pragma unroll
    for (int o = 1; o < 64; o <<= 1) {
      int t = __shfl_up(inc, o);
      if (lane >= o) inc += t;
    }
    if (lane == 63) s_wt[wave] = inc;
    __syncthreads();
    if (tid == 0) {
      int a = 0;
      for (int w = 0; w < kW; w++) {
        int t = s_wt[w];
        s_wt[w] = a;
        a += t;
      }
    }
    __syncthreads();
    const int texcl = s_wt[wave] + inc - sum;
#pragma unroll
    for (int j = 0; j < kCPT; j++) {
      int v = base + j;
      if (v < kNVOX) s_off[v] = texcl + local[j];
    }
  }
  __syncthreads();

  // ---- scatter (s_off becomes per-voxel END) ----
#pragma unroll
  for (int k = 0; k < kPPT; k++) {
    if (vid[k] >= 0) {
      int pos = atomicAdd(&s_off[vid[k]], 1);
      s_sorted[pos] = pt[k];
    }
  }
  __syncthreads();

  // ---- gather: 8 lanes per voxel, lane owns 4 channels ----
  const int grp = tid >> 3;      // 0..127
  const int gl  = tid & 7;       // channel quad
  float m0 = -FLT_MAX, m1 = -FLT_MAX, m2 = -FLT_MAX, m3 = -FLT_MAX;

  for (int v = grp; v < kNVOX; v += kGRP) {
    int cn = s_cnt[v];
    if (cn == 0) continue;
    int e = s_off[v];
    int b = e - cn;
    float a0 = 0.f, a1 = 0.f, a2 = 0.f, a3 = 0.f;
    for (int j = b; j < e; j++) {
      int p = s_sorted[j];
      const float4 f = *reinterpret_cast<const float4*>(
          &feats[(size_t)p * kC + gl * 4]);
      a0 += f.x; a1 += f.y; a2 += f.z; a3 += f.w;
    }
    float inv = 1.0f / (float)cn;
    // match reference: sum / cnt (division), use same expression
    m0 = fmaxf(m0, a0 / (float)cn);
    m1 = fmaxf(m1, a1 / (float)cn);
    m2 = fmaxf(m2, a2 / (float)cn);
    m3 = fmaxf(m3, a3 / (float)cn);
    (void)inv;
  }

  // reduce across the 8 groups within the wave (stride 8,16,32)
#pragma unroll
  for (int o = 8; o < 64; o <<= 1) {
    m0 = fmaxf(m0, __shfl_down(m0, o));
    m1 = fmaxf(m1, __shfl_down(m1, o));
    m2 = fmaxf(m2, __shfl_down(m2, o));
    m3 = fmaxf(m3, __shfl_down(m3, o));
  }
  if (lane < 8) {
    float* r = &s_redmax[wave * kC + lane * 4];
    r[0] = m0; r[1] = m1; r[2] = m2; r[3] = m3;
  }
  __syncthreads();
  if (tid < kC) {
    float mm = s_redmax[tid];
    for (int w = 1; w < kW; w++) mm = fmaxf(mm, s_redmax[w * kC + tid]);
    s_redmax[tid] = mm;
  }
  __syncthreads();

  // ---- score ----
  if (tid == 0) {
    float acc = bias[0];
    for (int j = 0; j < kC; j++) acc += s_redmax[j] * W[j];
    out[c] = acc;
  }
}

extern "C" void kernel_launch(void* const* d_in, const int* in_sizes, int n_in,
                              void* d_out, int out_size, void* d_ws,
                              size_t ws_size, hipStream_t stream) {
  const float* feats  = (const float*)d_in[0];
  const float* coords = (const float*)d_in[1];
  const float* W      = (const float*)d_in[2];
  const float* bias   = (const float*)d_in[3];
  const float* rand3  = (const float*)d_in[4];
  const int* cidx     = (const int*)d_in[5];
  const int* coff     = (const int*)d_in[6];
  float* out          = (float*)d_out;

  int nC = in_sizes[6] - 1;
  pg_kernel<<<nC, kBLK, 0, stream>>>(feats, coords, W, bias, rand3, cidx, coff,
                                     out);
}

// Round 4
// 50.648 us; speedup vs baseline: 4.5375x; 1.1141x over previous
//
#include <hip/hip_runtime.h>
#include <float.h>

// PointGroup R4: as R3 (block=1024, counting-sort, 8-lanes-per-voxel gather)
// plus 4-wide unrolled point loop in the gather phase: 4 independent
// global_load_dwordx4 in flight per lane instead of 1 (breaks the
// ds_read->global_load->acc serial chain that capped BW at 1.5 TB/s).

constexpr int kC    = 32;
constexpr int kFS   = 14;
constexpr int kNVOX = kFS * kFS * kFS;  // 2744
constexpr int kBLK  = 1024;
constexpr int kW    = kBLK / 64;        // 16 waves
constexpr int kPPT  = 2;                // points per thread (2048/1024)
constexpr int kPTS  = 2048;
constexpr int kCPT  = (kNVOX + kBLK - 1) / kBLK;  // 3 voxels per thread (scan)
constexpr int kGRP  = kBLK / 8;         // 128 voxel-groups

__device__ inline float wsum(float v) {
#pragma unroll
  for (int o = 32; o; o >>= 1) v += __shfl_down(v, o);
  return v;
}
__device__ inline float wmin(float v) {
#pragma unroll
  for (int o = 32; o; o >>= 1) v = fminf(v, __shfl_down(v, o));
  return v;
}
__device__ inline float wmax(float v) {
#pragma unroll
  for (int o = 32; o; o >>= 1) v = fmaxf(v, __shfl_down(v, o));
  return v;
}

__global__ __launch_bounds__(kBLK) void pg_kernel(
    const float* __restrict__ feats, const float* __restrict__ coords,
    const float* __restrict__ W, const float* __restrict__ bias,
    const float* __restrict__ rand3, const int* __restrict__ cidx,
    const int* __restrict__ coff, float* __restrict__ out) {
  __shared__ int s_cnt[kNVOX];
  __shared__ int s_off[kNVOX];
  __shared__ int s_sorted[kPTS];
  __shared__ float s_red[kW * 9];
  __shared__ float s_redmax[kW * kC];
  __shared__ float s_bcast[7];
  __shared__ int s_wt[kW];

  const int c = blockIdx.x;
  const int tid = threadIdx.x;
  const int lane = tid & 63, wave = tid >> 6;
  const int start = coff[c], end = coff[c + 1];

  // ---- Phase A: gather coords, reduce sum/min/max ----
  int pt[kPPT];
  float px[kPPT], py[kPPT], pz[kPPT];
  float sx = 0.f, sy = 0.f, sz = 0.f;
  float mnx = FLT_MAX, mny = FLT_MAX, mnz = FLT_MAX;
  float mxx = -FLT_MAX, mxy = -FLT_MAX, mxz = -FLT_MAX;
#pragma unroll
  for (int k = 0; k < kPPT; k++) {
    int i = start + tid + k * kBLK;
    if (i < end) {
      int p = cidx[2 * i + 1];
      pt[k] = p;
      float x = coords[3 * p + 0], y = coords[3 * p + 1], z = coords[3 * p + 2];
      px[k] = x; py[k] = y; pz[k] = z;
      sx += x; sy += y; sz += z;
      mnx = fminf(mnx, x); mny = fminf(mny, y); mnz = fminf(mnz, z);
      mxx = fmaxf(mxx, x); mxy = fmaxf(mxy, y); mxz = fmaxf(mxz, z);
    } else {
      pt[k] = -1;
    }
  }
  sx = wsum(sx); sy = wsum(sy); sz = wsum(sz);
  mnx = wmin(mnx); mny = wmin(mny); mnz = wmin(mnz);
  mxx = wmax(mxx); mxy = wmax(mxy); mxz = wmax(mxz);
  if (lane == 0) {
    float* r = &s_red[wave * 9];
    r[0] = sx; r[1] = sy; r[2] = sz;
    r[3] = mnx; r[4] = mny; r[5] = mnz;
    r[6] = mxx; r[7] = mxy; r[8] = mxz;
  }
  __syncthreads();
  if (tid == 0) {
    float Sx = s_red[0], Sy = s_red[1], Sz = s_red[2];
    float Mnx = s_red[3], Mny = s_red[4], Mnz = s_red[5];
    float Mxx = s_red[6], Mxy = s_red[7], Mxz = s_red[8];
    for (int w = 1; w < kW; w++) {
      const float* r = &s_red[w * 9];
      Sx += r[0]; Sy += r[1]; Sz += r[2];
      Mnx = fminf(Mnx, r[3]); Mny = fminf(Mny, r[4]); Mnz = fminf(Mnz, r[5]);
      Mxx = fmaxf(Mxx, r[6]); Mxy = fmaxf(Mxy, r[7]); Mxz = fmaxf(Mxz, r[8]);
    }
    float n = (float)(end - start);
    float cmx = Sx / n, cmy = Sy / n, cmz = Sz / n;
    float cminx = Mnx - cmx, cminy = Mny - cmy, cminz = Mnz - cmz;
    float cmaxx = Mxx - cmx, cmaxy = Mxy - cmy, cmaxz = Mxz - cmz;
    float r0 = (cmaxx - cminx) / 14.0f;
    float r1 = (cmaxy - cminy) / 14.0f;
    float r2 = (cmaxz - cminz) / 14.0f;
    float cs = 1.0f / fmaxf(fmaxf(r0, r1), r2) - 0.01f;
    cs = fminf(cs, 50.0f);
    float r3x = rand3[0], r3y = rand3[1], r3z = rand3[2];
    float mn0 = cminx * cs, mx0 = cmaxx * cs, b0 = mx0 - mn0;
    float mn1 = cminy * cs, mx1 = cmaxy * cs, b1 = mx1 - mn1;
    float mn2 = cminz * cs, mx2 = cmaxz * cs, b2 = mx2 - mn2;
    float ox = -mn0 + fmaxf(14.0f - b0 - 0.001f, 0.0f) * r3x +
               fminf(14.0f - b0 + 0.001f, 0.0f) * r3x;
    float oy = -mn1 + fmaxf(14.0f - b1 - 0.001f, 0.0f) * r3y +
               fminf(14.0f - b1 + 0.001f, 0.0f) * r3y;
    float oz = -mn2 + fmaxf(14.0f - b2 - 0.001f, 0.0f) * r3z +
               fminf(14.0f - b2 + 0.001f, 0.0f) * r3z;
    s_bcast[0] = cmx; s_bcast[1] = cmy; s_bcast[2] = cmz;
    s_bcast[3] = cs;
    s_bcast[4] = ox; s_bcast[5] = oy; s_bcast[6] = oz;
  }
  __syncthreads();
  const float cmx = s_bcast[0], cmy = s_bcast[1], cmz = s_bcast[2];
  const float cs = s_bcast[3];
  const float ox = s_bcast[4], oy = s_bcast[5], oz = s_bcast[6];

  // ---- voxel ids (reference FP op order) ----
  int vid[kPPT];
#pragma unroll
  for (int k = 0; k < kPPT; k++) {
    if (pt[k] >= 0) {
      float tx = (px[k] - cmx) * cs + ox;
      float ty = (py[k] - cmy) * cs + oy;
      float tz = (pz[k] - cmz) * cs + oz;
      int vx = min(kFS - 1, max(0, (int)floorf(tx)));
      int vy = min(kFS - 1, max(0, (int)floorf(ty)));
      int vz = min(kFS - 1, max(0, (int)floorf(tz)));
      vid[k] = (vx * kFS + vy) * kFS + vz;
    } else {
      vid[k] = -1;
    }
  }

  // ---- counting sort: counts ----
  for (int v = tid; v < kNVOX; v += kBLK) s_cnt[v] = 0;
  __syncthreads();
#pragma unroll
  for (int k = 0; k < kPPT; k++)
    if (vid[k] >= 0) atomicAdd(&s_cnt[vid[k]], 1);
  __syncthreads();

  // ---- exclusive prefix scan over s_cnt -> s_off ----
  {
    const int base = tid * kCPT;
    int local[kCPT];
    int sum = 0;
#pragma unroll
    for (int j = 0; j < kCPT; j++) {
      int v = base + j;
      int x = (v < kNVOX) ? s_cnt[v] : 0;
      local[j] = sum;
      sum += x;
    }
    int inc = sum;
#pragma unroll
    for (int o = 1; o < 64; o <<= 1) {
      int t = __shfl_up(inc, o);
      if (lane >= o) inc += t;
    }
    if (lane == 63) s_wt[wave] = inc;
    __syncthreads();
    if (tid == 0) {
      int a = 0;
      for (int w = 0; w < kW; w++) {
        int t = s_wt[w];
        s_wt[w] = a;
        a += t;
      }
    }
    __syncthreads();
    const int texcl = s_wt[wave] + inc - sum;
#pragma unroll
    for (int j = 0; j < kCPT; j++) {
      int v = base + j;
      if (v < kNVOX) s_off[v] = texcl + local[j];
    }
  }
  __syncthreads();

  // ---- scatter (s_off becomes per-voxel END) ----
#pragma unroll
  for (int k = 0; k < kPPT; k++) {
    if (vid[k] >= 0) {
      int pos = atomicAdd(&s_off[vid[k]], 1);
      s_sorted[pos] = pt[k];
    }
  }
  __syncthreads();

  // ---- gather: 8 lanes per voxel, lane owns 4 channels; 4-wide MLP ----
  const int grp = tid >> 3;      // 0..127
  const int gl  = tid & 7;       // channel quad
  const size_t chOff = (size_t)gl * 4;
  float m0 = -FLT_MAX, m1 = -FLT_MAX, m2 = -FLT_MAX, m3 = -FLT_MAX;

  for (int v = grp; v < kNVOX; v += kGRP) {
    int cn = s_cnt[v];
    if (cn == 0) continue;
    int e = s_off[v];
    int b = e - cn;
    float a0 = 0.f, a1 = 0.f, a2 = 0.f, a3 = 0.f;
    int j = b;
    for (; j + 4 <= e; j += 4) {
      int p0 = s_sorted[j + 0];
      int p1 = s_sorted[j + 1];
      int p2 = s_sorted[j + 2];
      int p3 = s_sorted[j + 3];
      const float4 f0 =
          *reinterpret_cast<const float4*>(&feats[(size_t)p0 * kC + chOff]);
      const float4 f1 =
          *reinterpret_cast<const float4*>(&feats[(size_t)p1 * kC + chOff]);
      const float4 f2 =
          *reinterpret_cast<const float4*>(&feats[(size_t)p2 * kC + chOff]);
      const float4 f3 =
          *reinterpret_cast<const float4*>(&feats[(size_t)p3 * kC + chOff]);
      a0 += f0.x + f1.x + f2.x + f3.x;
      a1 += f0.y + f1.y + f2.y + f3.y;
      a2 += f0.z + f1.z + f2.z + f3.z;
      a3 += f0.w + f1.w + f2.w + f3.w;
    }
    for (; j < e; j++) {
      int p = s_sorted[j];
      const float4 f =
          *reinterpret_cast<const float4*>(&feats[(size_t)p * kC + chOff]);
      a0 += f.x; a1 += f.y; a2 += f.z; a3 += f.w;
    }
    float fc = (float)cn;
    m0 = fmaxf(m0, a0 / fc);
    m1 = fmaxf(m1, a1 / fc);
    m2 = fmaxf(m2, a2 / fc);
    m3 = fmaxf(m3, a3 / fc);
  }

  // reduce across the 8 groups within the wave (stride 8,16,32)
#pragma unroll
  for (int o = 8; o < 64; o <<= 1) {
    m0 = fmaxf(m0, __shfl_down(m0, o));
    m1 = fmaxf(m1, __shfl_down(m1, o));
    m2 = fmaxf(m2, __shfl_down(m2, o));
    m3 = fmaxf(m3, __shfl_down(m3, o));
  }
  if (lane < 8) {
    float* r = &s_redmax[wave * kC + lane * 4];
    r[0] = m0; r[1] = m1; r[2] = m2; r[3] = m3;
  }
  __syncthreads();
  if (tid < kC) {
    float mm = s_redmax[tid];
    for (int w = 1; w < kW; w++) mm = fmaxf(mm, s_redmax[w * kC + tid]);
    s_redmax[tid] = mm;
  }
  __syncthreads();

  // ---- score ----
  if (tid == 0) {
    float acc = bias[0];
    for (int j = 0; j < kC; j++) acc += s_redmax[j] * W[j];
    out[c] = acc;
  }
}

extern "C" void kernel_launch(void* const* d_in, const int* in_sizes, int n_in,
                              void* d_out, int out_size, void* d_ws,
                              size_t ws_size, hipStream_t stream) {
  const float* feats  = (const float*)d_in[0];
  const float* coords = (const float*)d_in[1];
  const float* W      = (const float*)d_in[2];
  const float* bias   = (const float*)d_in[3];
  const float* rand3  = (const float*)d_in[4];
  const int* cidx     = (const int*)d_in[5];
  const int* coff     = (const int*)d_in[6];
  float* out          = (float*)d_out;

  int nC = in_sizes[6] - 1;
  pg_kernel<<<nC, kBLK, 0, stream>>>(feats, coords, W, bias, rand3, cidx, coff,
                                     out);
}

// Round 5
// 46.805 us; speedup vs baseline: 4.9101x; 1.0821x over previous
//
#include <hip/hip_runtime.h>
#include <float.h>

// PointGroup R5: flat-run gather. Scatter also records per-position voxel id
// (s_pvid). Each 8-lane group owns sorted positions [16g,16g+16): processes
// exactly the voxels whose runs START in its window -> ~16 pts/group balanced,
// one contiguous point stream per group, software-pipelined 8-deep (8
// independent global_load_dwordx4 in flight/lane) with boundary-aware
// finalize. Removes R4's empty-voxel divergence and short serial chains.

constexpr int kC    = 32;
constexpr int kFS   = 14;
constexpr int kNVOX = kFS * kFS * kFS;  // 2744
constexpr int kBLK  = 1024;
constexpr int kW    = kBLK / 64;        // 16 waves
constexpr int kPPT  = 2;                // points per thread (2048/1024)
constexpr int kPTS  = 2048;
constexpr int kCPT  = (kNVOX + kBLK - 1) / kBLK;  // 3 voxels per thread (scan)
constexpr int kGPW  = 16;               // points-window per group

__device__ inline float wsum(float v) {
#pragma unroll
  for (int o = 32; o; o >>= 1) v += __shfl_down(v, o);
  return v;
}
__device__ inline float wmin(float v) {
#pragma unroll
  for (int o = 32; o; o >>= 1) v = fminf(v, __shfl_down(v, o));
  return v;
}
__device__ inline float wmax(float v) {
#pragma unroll
  for (int o = 32; o; o >>= 1) v = fmaxf(v, __shfl_down(v, o));
  return v;
}

__global__ __launch_bounds__(kBLK) void pg_kernel(
    const float* __restrict__ feats, const float* __restrict__ coords,
    const float* __restrict__ W, const float* __restrict__ bias,
    const float* __restrict__ rand3, const int* __restrict__ cidx,
    const int* __restrict__ coff, float* __restrict__ out) {
  __shared__ int s_cnt[kNVOX];
  __shared__ int s_off[kNVOX];     // after scatter: per-voxel END position
  __shared__ int s_sorted[kPTS];   // point ids sorted by voxel
  __shared__ int s_pvid[kPTS];     // voxel id per sorted position
  __shared__ float s_red[kW * 9];
  __shared__ float s_redmax[kW * kC];
  __shared__ float s_bcast[7];
  __shared__ int s_wt[kW];

  const int c = blockIdx.x;
  const int tid = threadIdx.x;
  const int lane = tid & 63, wave = tid >> 6;
  const int start = coff[c], end = coff[c + 1];
  const int npts = end - start;

  // ---- Phase A: gather coords, reduce sum/min/max ----
  int pt[kPPT];
  float px[kPPT], py[kPPT], pz[kPPT];
  float sx = 0.f, sy = 0.f, sz = 0.f;
  float mnx = FLT_MAX, mny = FLT_MAX, mnz = FLT_MAX;
  float mxx = -FLT_MAX, mxy = -FLT_MAX, mxz = -FLT_MAX;
#pragma unroll
  for (int k = 0; k < kPPT; k++) {
    int i = start + tid + k * kBLK;
    if (i < end) {
      int p = cidx[2 * i + 1];
      pt[k] = p;
      float x = coords[3 * p + 0], y = coords[3 * p + 1], z = coords[3 * p + 2];
      px[k] = x; py[k] = y; pz[k] = z;
      sx += x; sy += y; sz += z;
      mnx = fminf(mnx, x); mny = fminf(mny, y); mnz = fminf(mnz, z);
      mxx = fmaxf(mxx, x); mxy = fmaxf(mxy, y); mxz = fmaxf(mxz, z);
    } else {
      pt[k] = -1;
    }
  }
  sx = wsum(sx); sy = wsum(sy); sz = wsum(sz);
  mnx = wmin(mnx); mny = wmin(mny); mnz = wmin(mnz);
  mxx = wmax(mxx); mxy = wmax(mxy); mxz = wmax(mxz);
  if (lane == 0) {
    float* r = &s_red[wave * 9];
    r[0] = sx; r[1] = sy; r[2] = sz;
    r[3] = mnx; r[4] = mny; r[5] = mnz;
    r[6] = mxx; r[7] = mxy; r[8] = mxz;
  }
  __syncthreads();
  if (tid == 0) {
    float Sx = s_red[0], Sy = s_red[1], Sz = s_red[2];
    float Mnx = s_red[3], Mny = s_red[4], Mnz = s_red[5];
    float Mxx = s_red[6], Mxy = s_red[7], Mxz = s_red[8];
    for (int w = 1; w < kW; w++) {
      const float* r = &s_red[w * 9];
      Sx += r[0]; Sy += r[1]; Sz += r[2];
      Mnx = fminf(Mnx, r[3]); Mny = fminf(Mny, r[4]); Mnz = fminf(Mnz, r[5]);
      Mxx = fmaxf(Mxx, r[6]); Mxy = fmaxf(Mxy, r[7]); Mxz = fmaxf(Mxz, r[8]);
    }
    float n = (float)npts;
    float cmx = Sx / n, cmy = Sy / n, cmz = Sz / n;
    float cminx = Mnx - cmx, cminy = Mny - cmy, cminz = Mnz - cmz;
    float cmaxx = Mxx - cmx, cmaxy = Mxy - cmy, cmaxz = Mxz - cmz;
    float r0 = (cmaxx - cminx) / 14.0f;
    float r1 = (cmaxy - cminy) / 14.0f;
    float r2 = (cmaxz - cminz) / 14.0f;
    float cs = 1.0f / fmaxf(fmaxf(r0, r1), r2) - 0.01f;
    cs = fminf(cs, 50.0f);
    float r3x = rand3[0], r3y = rand3[1], r3z = rand3[2];
    float mn0 = cminx * cs, mx0 = cmaxx * cs, b0 = mx0 - mn0;
    float mn1 = cminy * cs, mx1 = cmaxy * cs, b1 = mx1 - mn1;
    float mn2 = cminz * cs, mx2 = cmaxz * cs, b2 = mx2 - mn2;
    float ox = -mn0 + fmaxf(14.0f - b0 - 0.001f, 0.0f) * r3x +
               fminf(14.0f - b0 + 0.001f, 0.0f) * r3x;
    float oy = -mn1 + fmaxf(14.0f - b1 - 0.001f, 0.0f) * r3y +
               fminf(14.0f - b1 + 0.001f, 0.0f) * r3y;
    float oz = -mn2 + fmaxf(14.0f - b2 - 0.001f, 0.0f) * r3z +
               fminf(14.0f - b2 + 0.001f, 0.0f) * r3z;
    s_bcast[0] = cmx; s_bcast[1] = cmy; s_bcast[2] = cmz;
    s_bcast[3] = cs;
    s_bcast[4] = ox; s_bcast[5] = oy; s_bcast[6] = oz;
  }
  __syncthreads();
  const float cmx = s_bcast[0], cmy = s_bcast[1], cmz = s_bcast[2];
  const float cs = s_bcast[3];
  const float ox = s_bcast[4], oy = s_bcast[5], oz = s_bcast[6];

  // ---- voxel ids (reference FP op order) ----
  int vid[kPPT];
#pragma unroll
  for (int k = 0; k < kPPT; k++) {
    if (pt[k] >= 0) {
      float tx = (px[k] - cmx) * cs + ox;
      float ty = (py[k] - cmy) * cs + oy;
      float tz = (pz[k] - cmz) * cs + oz;
      int vx = min(kFS - 1, max(0, (int)floorf(tx)));
      int vy = min(kFS - 1, max(0, (int)floorf(ty)));
      int vz = min(kFS - 1, max(0, (int)floorf(tz)));
      vid[k] = (vx * kFS + vy) * kFS + vz;
    } else {
      vid[k] = -1;
    }
  }

  // ---- counting sort: counts ----
  for (int v = tid; v < kNVOX; v += kBLK) s_cnt[v] = 0;
  __syncthreads();
#pragma unroll
  for (int k = 0; k < kPPT; k++)
    if (vid[k] >= 0) atomicAdd(&s_cnt[vid[k]], 1);
  __syncthreads();

  // ---- exclusive prefix scan over s_cnt -> s_off ----
  {
    const int base = tid * kCPT;
    int local[kCPT];
    int sum = 0;
#pragma unroll
    for (int j = 0; j < kCPT; j++) {
      int v = base + j;
      int x = (v < kNVOX) ? s_cnt[v] : 0;
      local[j] = sum;
      sum += x;
    }
    int inc = sum;
#pragma unroll
    for (int o = 1; o < 64; o <<= 1) {
      int t = __shfl_up(inc, o);
      if (lane >= o) inc += t;
    }
    if (lane == 63) s_wt[wave] = inc;
    __syncthreads();
    if (tid == 0) {
      int a = 0;
      for (int w = 0; w < kW; w++) {
        int t = s_wt[w];
        s_wt[w] = a;
        a += t;
      }
    }
    __syncthreads();
    const int texcl = s_wt[wave] + inc - sum;
#pragma unroll
    for (int j = 0; j < kCPT; j++) {
      int v = base + j;
      if (v < kNVOX) s_off[v] = texcl + local[j];
    }
  }
  __syncthreads();

  // ---- scatter (s_off becomes per-voxel END); record pos->vid ----
#pragma unroll
  for (int k = 0; k < kPPT; k++) {
    if (vid[k] >= 0) {
      int pos = atomicAdd(&s_off[vid[k]], 1);
      s_sorted[pos] = pt[k];
      s_pvid[pos] = vid[k];
    }
  }
  __syncthreads();

  // ---- flat-run gather: group g owns voxels STARTING in [16g, 16g+16) ----
  const int grp = tid >> 3;               // 0..127
  const int gl  = tid & 7;                // channel quad
  const size_t chOff = (size_t)gl * 4;
  float m0 = -FLT_MAX, m1 = -FLT_MAX, m2 = -FLT_MAX, m3 = -FLT_MAX;

  {
    const int p0 = grp * kGPW;
    if (p0 < npts) {
      const int p1 = min(p0 + kGPW, npts);
      // skip head run continuing from previous window
      int s = p0;
      {
        int v0 = s_pvid[p0];
        if (p0 > 0 && s_pvid[p0 - 1] == v0) s = s_off[v0];  // end of that run
      }
      if (s < p1) {
        // end of last voxel starting in window
        int pend = s;
        while (pend < p1) pend += s_cnt[s_pvid[pend]];

        int curv = -1;
        float a0 = 0.f, a1 = 0.f, a2 = 0.f, a3 = 0.f;
        for (int base = s; base < pend; base += 8) {
          float4 f0, f1, f2, f3, f4, f5, f6, f7;
          const int m = pend - base;
          // issue up to 8 independent loads
          if (m > 0) f0 = *reinterpret_cast<const float4*>(&feats[(size_t)s_sorted[base + 0] * kC + chOff]);
          if (m > 1) f1 = *reinterpret_cast<const float4*>(&feats[(size_t)s_sorted[base + 1] * kC + chOff]);
          if (m > 2) f2 = *reinterpret_cast<const float4*>(&feats[(size_t)s_sorted[base + 2] * kC + chOff]);
          if (m > 3) f3 = *reinterpret_cast<const float4*>(&feats[(size_t)s_sorted[base + 3] * kC + chOff]);
          if (m > 4) f4 = *reinterpret_cast<const float4*>(&feats[(size_t)s_sorted[base + 4] * kC + chOff]);
          if (m > 5) f5 = *reinterpret_cast<const float4*>(&feats[(size_t)s_sorted[base + 5] * kC + chOff]);
          if (m > 6) f6 = *reinterpret_cast<const float4*>(&feats[(size_t)s_sorted[base + 6] * kC + chOff]);
          if (m > 7) f7 = *reinterpret_cast<const float4*>(&feats[(size_t)s_sorted[base + 7] * kC + chOff]);
#define PG_ACC(K, F)                                                       \
          if (m > K) {                                                     \
            int vv = s_pvid[base + K];                                     \
            if (vv != curv) {                                              \
              if (curv >= 0) {                                             \
                float fc = (float)s_cnt[curv];                             \
                m0 = fmaxf(m0, a0 / fc); m1 = fmaxf(m1, a1 / fc);          \
                m2 = fmaxf(m2, a2 / fc); m3 = fmaxf(m3, a3 / fc);          \
              }                                                            \
              curv = vv; a0 = a1 = a2 = a3 = 0.f;                          \
            }                                                              \
            a0 += F.x; a1 += F.y; a2 += F.z; a3 += F.w;                    \
          }
          PG_ACC(0, f0) PG_ACC(1, f1) PG_ACC(2, f2) PG_ACC(3, f3)
          PG_ACC(4, f4) PG_ACC(5, f5) PG_ACC(6, f6) PG_ACC(7, f7)
#undef PG_ACC
        }
        if (curv >= 0) {
          float fc = (float)s_cnt[curv];
          m0 = fmaxf(m0, a0 / fc); m1 = fmaxf(m1, a1 / fc);
          m2 = fmaxf(m2, a2 / fc); m3 = fmaxf(m3, a3 / fc);
        }
      }
    }
  }

  // reduce across the 8 groups within the wave (stride 8,16,32)
#pragma unroll
  for (int o = 8; o < 64; o <<= 1) {
    m0 = fmaxf(m0, __shfl_down(m0, o));
    m1 = fmaxf(m1, __shfl_down(m1, o));
    m2 = fmaxf(m2, __shfl_down(m2, o));
    m3 = fmaxf(m3, __shfl_down(m3, o));
  }
  if (lane < 8) {
    float* r = &s_redmax[wave * kC + lane * 4];
    r[0] = m0; r[1] = m1; r[2] = m2; r[3] = m3;
  }
  __syncthreads();
  if (tid < kC) {
    float mm = s_redmax[tid];
    for (int w = 1; w < kW; w++) mm = fmaxf(mm, s_redmax[w * kC + tid]);
    s_redmax[tid] = mm;
  }
  __syncthreads();

  // ---- score ----
  if (tid == 0) {
    float acc = bias[0];
    for (int j = 0; j < kC; j++) acc += s_redmax[j] * W[j];
    out[c] = acc;
  }
}

extern "C" void kernel_launch(void* const* d_in, const int* in_sizes, int n_in,
                              void* d_out, int out_size, void* d_ws,
                              size_t ws_size, hipStream_t stream) {
  const float* feats  = (const float*)d_in[0];
  const float* coords = (const float*)d_in[1];
  const float* W      = (const float*)d_in[2];
  const float* bias   = (const float*)d_in[3];
  const float* rand3  = (const float*)d_in[4];
  const int* cidx     = (const int*)d_in[5];
  const int* coff     = (const int*)d_in[6];
  float* out          = (float*)d_out;

  int nC = in_sizes[6] - 1;
  pg_kernel<<<nC, kBLK, 0, stream>>>(feats, coords, W, bias, rand3, cidx, coff,
                                     out);
}

// Round 6
// 46.748 us; speedup vs baseline: 4.9160x; 1.0012x over previous
//
#include <hip/hip_runtime.h>
#include <float.h>

// PointGroup R6: R5's flat-run gather with the pipeline made REAL:
// - 8 UNCONDITIONAL clamped-index global_load_dwordx4 per chunk (compiler
//   cannot sink them; guards only on the accumulate) -> true 8-deep MLP.
// - (vid<<20)|pid packed into one u32 in LDS: 8 ds_reads/chunk instead of 16.
// - run head/end via direct s_off lookups instead of serial run-walk.
// - __launch_bounds__(1024,8) pins VGPR<=64 to keep 2 blocks/CU (32 waves).

constexpr int kC    = 32;
constexpr int kFS   = 14;
constexpr int kNVOX = kFS * kFS * kFS;  // 2744
constexpr int kBLK  = 1024;
constexpr int kW    = kBLK / 64;        // 16 waves
constexpr int kPPT  = 2;                // points per thread (2048/1024)
constexpr int kPTS  = 2048;
constexpr int kCPT  = (kNVOX + kBLK - 1) / kBLK;  // 3 voxels per thread (scan)
constexpr int kGPW  = 16;               // points-window per group

__device__ inline float wsum(float v) {
#pragma unroll
  for (int o = 32; o; o >>= 1) v += __shfl_down(v, o);
  return v;
}
__device__ inline float wmin(float v) {
#pragma unroll
  for (int o = 32; o; o >>= 1) v = fminf(v, __shfl_down(v, o));
  return v;
}
__device__ inline float wmax(float v) {
#pragma unroll
  for (int o = 32; o; o >>= 1) v = fmaxf(v, __shfl_down(v, o));
  return v;
}

__global__ __launch_bounds__(kBLK, 8) void pg_kernel(
    const float* __restrict__ feats, const float* __restrict__ coords,
    const float* __restrict__ W, const float* __restrict__ bias,
    const float* __restrict__ rand3, const int* __restrict__ cidx,
    const int* __restrict__ coff, float* __restrict__ out) {
  __shared__ int s_cnt[kNVOX];
  __shared__ int s_off[kNVOX];     // after scatter: per-voxel END position
  __shared__ unsigned s_pack[kPTS];  // (vid<<20) | pid per sorted position
  __shared__ float s_red[kW * 9];
  __shared__ float s_redmax[kW * kC];
  __shared__ float s_bcast[7];
  __shared__ int s_wt[kW];

  const int c = blockIdx.x;
  const int tid = threadIdx.x;
  const int lane = tid & 63, wave = tid >> 6;
  const int start = coff[c], end = coff[c + 1];
  const int npts = end - start;

  // ---- Phase A: gather coords, reduce sum/min/max ----
  int pt[kPPT];
  float px[kPPT], py[kPPT], pz[kPPT];
  float sx = 0.f, sy = 0.f, sz = 0.f;
  float mnx = FLT_MAX, mny = FLT_MAX, mnz = FLT_MAX;
  float mxx = -FLT_MAX, mxy = -FLT_MAX, mxz = -FLT_MAX;
#pragma unroll
  for (int k = 0; k < kPPT; k++) {
    int i = start + tid + k * kBLK;
    if (i < end) {
      int p = cidx[2 * i + 1];
      pt[k] = p;
      float x = coords[3 * p + 0], y = coords[3 * p + 1], z = coords[3 * p + 2];
      px[k] = x; py[k] = y; pz[k] = z;
      sx += x; sy += y; sz += z;
      mnx = fminf(mnx, x); mny = fminf(mny, y); mnz = fminf(mnz, z);
      mxx = fmaxf(mxx, x); mxy = fmaxf(mxy, y); mxz = fmaxf(mxz, z);
    } else {
      pt[k] = -1;
    }
  }
  sx = wsum(sx); sy = wsum(sy); sz = wsum(sz);
  mnx = wmin(mnx); mny = wmin(mny); mnz = wmin(mnz);
  mxx = wmax(mxx); mxy = wmax(mxy); mxz = wmax(mxz);
  if (lane == 0) {
    float* r = &s_red[wave * 9];
    r[0] = sx; r[1] = sy; r[2] = sz;
    r[3] = mnx; r[4] = mny; r[5] = mnz;
    r[6] = mxx; r[7] = mxy; r[8] = mxz;
  }
  __syncthreads();
  if (tid == 0) {
    float Sx = s_red[0], Sy = s_red[1], Sz = s_red[2];
    float Mnx = s_red[3], Mny = s_red[4], Mnz = s_red[5];
    float Mxx = s_red[6], Mxy = s_red[7], Mxz = s_red[8];
    for (int w = 1; w < kW; w++) {
      const float* r = &s_red[w * 9];
      Sx += r[0]; Sy += r[1]; Sz += r[2];
      Mnx = fminf(Mnx, r[3]); Mny = fminf(Mny, r[4]); Mnz = fminf(Mnz, r[5]);
      Mxx = fmaxf(Mxx, r[6]); Mxy = fmaxf(Mxy, r[7]); Mxz = fmaxf(Mxz, r[8]);
    }
    float n = (float)npts;
    float cmx = Sx / n, cmy = Sy / n, cmz = Sz / n;
    float cminx = Mnx - cmx, cminy = Mny - cmy, cminz = Mnz - cmz;
    float cmaxx = Mxx - cmx, cmaxy = Mxy - cmy, cmaxz = Mxz - cmz;
    float r0 = (cmaxx - cminx) / 14.0f;
    float r1 = (cmaxy - cminy) / 14.0f;
    float r2 = (cmaxz - cminz) / 14.0f;
    float cs = 1.0f / fmaxf(fmaxf(r0, r1), r2) - 0.01f;
    cs = fminf(cs, 50.0f);
    float r3x = rand3[0], r3y = rand3[1], r3z = rand3[2];
    float mn0 = cminx * cs, mx0 = cmaxx * cs, b0 = mx0 - mn0;
    float mn1 = cminy * cs, mx1 = cmaxy * cs, b1 = mx1 - mn1;
    float mn2 = cminz * cs, mx2 = cmaxz * cs, b2 = mx2 - mn2;
    float ox = -mn0 + fmaxf(14.0f - b0 - 0.001f, 0.0f) * r3x +
               fminf(14.0f - b0 + 0.001f, 0.0f) * r3x;
    float oy = -mn1 + fmaxf(14.0f - b1 - 0.001f, 0.0f) * r3y +
               fminf(14.0f - b1 + 0.001f, 0.0f) * r3y;
    float oz = -mn2 + fmaxf(14.0f - b2 - 0.001f, 0.0f) * r3z +
               fminf(14.0f - b2 + 0.001f, 0.0f) * r3z;
    s_bcast[0] = cmx; s_bcast[1] = cmy; s_bcast[2] = cmz;
    s_bcast[3] = cs;
    s_bcast[4] = ox; s_bcast[5] = oy; s_bcast[6] = oz;
  }
  __syncthreads();
  const float cmx = s_bcast[0], cmy = s_bcast[1], cmz = s_bcast[2];
  const float cs = s_bcast[3];
  const float ox = s_bcast[4], oy = s_bcast[5], oz = s_bcast[6];

  // ---- voxel ids (reference FP op order) ----
  int vid[kPPT];
#pragma unroll
  for (int k = 0; k < kPPT; k++) {
    if (pt[k] >= 0) {
      float tx = (px[k] - cmx) * cs + ox;
      float ty = (py[k] - cmy) * cs + oy;
      float tz = (pz[k] - cmz) * cs + oz;
      int vx = min(kFS - 1, max(0, (int)floorf(tx)));
      int vy = min(kFS - 1, max(0, (int)floorf(ty)));
      int vz = min(kFS - 1, max(0, (int)floorf(tz)));
      vid[k] = (vx * kFS + vy) * kFS + vz;
    } else {
      vid[k] = -1;
    }
  }

  // ---- counting sort: counts ----
  for (int v = tid; v < kNVOX; v += kBLK) s_cnt[v] = 0;
  __syncthreads();
#pragma unroll
  for (int k = 0; k < kPPT; k++)
    if (vid[k] >= 0) atomicAdd(&s_cnt[vid[k]], 1);
  __syncthreads();

  // ---- exclusive prefix scan over s_cnt -> s_off ----
  {
    const int base = tid * kCPT;
    int local[kCPT];
    int sum = 0;
#pragma unroll
    for (int j = 0; j < kCPT; j++) {
      int v = base + j;
      int x = (v < kNVOX) ? s_cnt[v] : 0;
      local[j] = sum;
      sum += x;
    }
    int inc = sum;
#pragma unroll
    for (int o = 1; o < 64; o <<= 1) {
      int t = __shfl_up(inc, o);
      if (lane >= o) inc += t;
    }
    if (lane == 63) s_wt[wave] = inc;
    __syncthreads();
    if (tid == 0) {
      int a = 0;
      for (int w = 0; w < kW; w++) {
        int t = s_wt[w];
        s_wt[w] = a;
        a += t;
      }
    }
    __syncthreads();
    const int texcl = s_wt[wave] + inc - sum;
#pragma unroll
    for (int j = 0; j < kCPT; j++) {
      int v = base + j;
      if (v < kNVOX) s_off[v] = texcl + local[j];
    }
  }
  __syncthreads();

  // ---- scatter (s_off becomes per-voxel END); pack (vid<<20)|pid ----
#pragma unroll
  for (int k = 0; k < kPPT; k++) {
    if (vid[k] >= 0) {
      int pos = atomicAdd(&s_off[vid[k]], 1);
      s_pack[pos] = ((unsigned)vid[k] << 20) | (unsigned)pt[k];
    }
  }
  __syncthreads();

  // ---- flat-run gather: group g owns voxels STARTING in [16g, 16g+16) ----
  const int grp = tid >> 3;               // 0..127
  const int gl  = tid & 7;                // channel quad
  const size_t chOff = (size_t)gl * 4;
  float m0 = -FLT_MAX, m1 = -FLT_MAX, m2 = -FLT_MAX, m3 = -FLT_MAX;

  {
    const int p0 = grp * kGPW;
    if (p0 < npts) {
      const int p1 = min(p0 + kGPW, npts);
      const int v0 = (int)(s_pack[p0] >> 20);
      // skip head run continuing from previous window (s_off[v] = run END)
      int s = p0;
      if (p0 > 0 && (int)(s_pack[p0 - 1] >> 20) == v0) s = s_off[v0];
      // end of the run containing the window's last position
      const int vend = (int)(s_pack[p1 - 1] >> 20);
      const int pend = s_off[vend];  // if head run covers window: pend==s

      int curv = -1;
      float a0 = 0.f, a1 = 0.f, a2 = 0.f, a3 = 0.f;
      for (int base = s; base < pend; base += 8) {
        // clamped sorted positions -> ALL 8 loads unconditional & independent
        const int j0 = base + 0, j1 = min(base + 1, pend - 1),
                  j2 = min(base + 2, pend - 1), j3 = min(base + 3, pend - 1),
                  j4 = min(base + 4, pend - 1), j5 = min(base + 5, pend - 1),
                  j6 = min(base + 6, pend - 1), j7 = min(base + 7, pend - 1);
        const unsigned w0 = s_pack[j0], w1 = s_pack[j1], w2 = s_pack[j2],
                       w3 = s_pack[j3], w4 = s_pack[j4], w5 = s_pack[j5],
                       w6 = s_pack[j6], w7 = s_pack[j7];
        const float4 f0 = *reinterpret_cast<const float4*>(
            &feats[(size_t)(w0 & 0xFFFFFu) * kC + chOff]);
        const float4 f1 = *reinterpret_cast<const float4*>(
            &feats[(size_t)(w1 & 0xFFFFFu) * kC + chOff]);
        const float4 f2 = *reinterpret_cast<const float4*>(
            &feats[(size_t)(w2 & 0xFFFFFu) * kC + chOff]);
        const float4 f3 = *reinterpret_cast<const float4*>(
            &feats[(size_t)(w3 & 0xFFFFFu) * kC + chOff]);
        const float4 f4 = *reinterpret_cast<const float4*>(
            &feats[(size_t)(w4 & 0xFFFFFu) * kC + chOff]);
        const float4 f5 = *reinterpret_cast<const float4*>(
            &feats[(size_t)(w5 & 0xFFFFFu) * kC + chOff]);
        const float4 f6 = *reinterpret_cast<const float4*>(
            &feats[(size_t)(w6 & 0xFFFFFu) * kC + chOff]);
        const float4 f7 = *reinterpret_cast<const float4*>(
            &feats[(size_t)(w7 & 0xFFFFFu) * kC + chOff]);
        const int m = pend - base;
#define PG_ACC(K, WK, FK)                                                  \
        if (m > K) {                                                       \
          const int vv = (int)(WK >> 20);                                  \
          if (vv != curv) {                                                \
            if (curv >= 0) {                                               \
              const float fc = (float)s_cnt[curv];                         \
              m0 = fmaxf(m0, a0 / fc); m1 = fmaxf(m1, a1 / fc);            \
              m2 = fmaxf(m2, a2 / fc); m3 = fmaxf(m3, a3 / fc);            \
            }                                                              \
            curv = vv; a0 = a1 = a2 = a3 = 0.f;                            \
          }                                                                \
          a0 += FK.x; a1 += FK.y; a2 += FK.z; a3 += FK.w;                  \
        }
        PG_ACC(0, w0, f0) PG_ACC(1, w1, f1) PG_ACC(2, w2, f2)
        PG_ACC(3, w3, f3) PG_ACC(4, w4, f4) PG_ACC(5, w5, f5)
        PG_ACC(6, w6, f6) PG_ACC(7, w7, f7)
#undef PG_ACC
      }
      if (curv >= 0) {
        const float fc = (float)s_cnt[curv];
        m0 = fmaxf(m0, a0 / fc); m1 = fmaxf(m1, a1 / fc);
        m2 = fmaxf(m2, a2 / fc); m3 = fmaxf(m3, a3 / fc);
      }
    }
  }

  // reduce across the 8 groups within the wave (stride 8,16,32)
#pragma unroll
  for (int o = 8; o < 64; o <<= 1) {
    m0 = fmaxf(m0, __shfl_down(m0, o));
    m1 = fmaxf(m1, __shfl_down(m1, o));
    m2 = fmaxf(m2, __shfl_down(m2, o));
    m3 = fmaxf(m3, __shfl_down(m3, o));
  }
  if (lane < 8) {
    float* r = &s_redmax[wave * kC + lane * 4];
    r[0] = m0; r[1] = m1; r[2] = m2; r[3] = m3;
  }
  __syncthreads();
  if (tid < kC) {
    float mm = s_redmax[tid];
    for (int w = 1; w < kW; w++) mm = fmaxf(mm, s_redmax[w * kC + tid]);
    s_redmax[tid] = mm;
  }
  __syncthreads();

  // ---- score ----
  if (tid == 0) {
    float acc = bias[0];
    for (int j = 0; j < kC; j++) acc += s_redmax[j] * W[j];
    out[c] = acc;
  }
}

extern "C" void kernel_launch(void* const* d_in, const int* in_sizes, int n_in,
                              void* d_out, int out_size, void* d_ws,
                              size_t ws_size, hipStream_t stream) {
  const float* feats  = (const float*)d_in[0];
  const float* coords = (const float*)d_in[1];
  const float* W      = (const float*)d_in[2];
  const float* bias   = (const float*)d_in[3];
  const float* rand3  = (const float*)d_in[4];
  const int* cidx     = (const int*)d_in[5];
  const int* coff     = (const int*)d_in[6];
  float* out          = (float*)d_out;

  int nC = in_sizes[6] - 1;
  pg_kernel<<<nC, kBLK, 0, stream>>>(feats, coords, W, bias, rand3, cidx, coff,
                                     out);
}

// Round 7
// 44.295 us; speedup vs baseline: 5.1883x; 1.0554x over previous
//
#include <hip/hip_runtime.h>
#include <float.h>

// PointGroup R7: R6 structure + division elimination in the gather hot loop.
// - s_rinv[v] = 1/cnt precomputed during the scan phase (parallel, ~free).
// - run finalize = 4 mul + 4 max (was 4 full-precision fdiv ~40 instrs under
//   divergent exec masks at ~60% of positions).
// - run start: a = F directly, rin fetched early (LDS latency hidden).
// - gather phase no longer reads s_cnt.

constexpr int kC    = 32;
constexpr int kFS   = 14;
constexpr int kNVOX = kFS * kFS * kFS;  // 2744
constexpr int kBLK  = 1024;
constexpr int kW    = kBLK / 64;        // 16 waves
constexpr int kPPT  = 2;                // points per thread (2048/1024)
constexpr int kPTS  = 2048;
constexpr int kCPT  = (kNVOX + kBLK - 1) / kBLK;  // 3 voxels per thread (scan)
constexpr int kGPW  = 16;               // points-window per group

__device__ inline float wsum(float v) {
#pragma unroll
  for (int o = 32; o; o >>= 1) v += __shfl_down(v, o);
  return v;
}
__device__ inline float wmin(float v) {
#pragma unroll
  for (int o = 32; o; o >>= 1) v = fminf(v, __shfl_down(v, o));
  return v;
}
__device__ inline float wmax(float v) {
#pragma unroll
  for (int o = 32; o; o >>= 1) v = fmaxf(v, __shfl_down(v, o));
  return v;
}

__global__ __launch_bounds__(kBLK, 8) void pg_kernel(
    const float* __restrict__ feats, const float* __restrict__ coords,
    const float* __restrict__ W, const float* __restrict__ bias,
    const float* __restrict__ rand3, const int* __restrict__ cidx,
    const int* __restrict__ coff, float* __restrict__ out) {
  __shared__ int s_cnt[kNVOX];
  __shared__ int s_off[kNVOX];       // after scatter: per-voxel END position
  __shared__ float s_rinv[kNVOX];    // 1/cnt per voxel
  __shared__ unsigned s_pack[kPTS];  // (vid<<20) | pid per sorted position
  __shared__ float s_red[kW * 9];
  __shared__ float s_redmax[kW * kC];
  __shared__ float s_bcast[7];
  __shared__ int s_wt[kW];

  const int c = blockIdx.x;
  const int tid = threadIdx.x;
  const int lane = tid & 63, wave = tid >> 6;
  const int start = coff[c], end = coff[c + 1];
  const int npts = end - start;

  // ---- Phase A: gather coords, reduce sum/min/max ----
  int pt[kPPT];
  float px[kPPT], py[kPPT], pz[kPPT];
  float sx = 0.f, sy = 0.f, sz = 0.f;
  float mnx = FLT_MAX, mny = FLT_MAX, mnz = FLT_MAX;
  float mxx = -FLT_MAX, mxy = -FLT_MAX, mxz = -FLT_MAX;
#pragma unroll
  for (int k = 0; k < kPPT; k++) {
    int i = start + tid + k * kBLK;
    if (i < end) {
      int p = cidx[2 * i + 1];
      pt[k] = p;
      float x = coords[3 * p + 0], y = coords[3 * p + 1], z = coords[3 * p + 2];
      px[k] = x; py[k] = y; pz[k] = z;
      sx += x; sy += y; sz += z;
      mnx = fminf(mnx, x); mny = fminf(mny, y); mnz = fminf(mnz, z);
      mxx = fmaxf(mxx, x); mxy = fmaxf(mxy, y); mxz = fmaxf(mxz, z);
    } else {
      pt[k] = -1;
    }
  }
  sx = wsum(sx); sy = wsum(sy); sz = wsum(sz);
  mnx = wmin(mnx); mny = wmin(mny); mnz = wmin(mnz);
  mxx = wmax(mxx); mxy = wmax(mxy); mxz = wmax(mxz);
  if (lane == 0) {
    float* r = &s_red[wave * 9];
    r[0] = sx; r[1] = sy; r[2] = sz;
    r[3] = mnx; r[4] = mny; r[5] = mnz;
    r[6] = mxx; r[7] = mxy; r[8] = mxz;
  }
  __syncthreads();
  if (tid == 0) {
    float Sx = s_red[0], Sy = s_red[1], Sz = s_red[2];
    float Mnx = s_red[3], Mny = s_red[4], Mnz = s_red[5];
    float Mxx = s_red[6], Mxy = s_red[7], Mxz = s_red[8];
    for (int w = 1; w < kW; w++) {
      const float* r = &s_red[w * 9];
      Sx += r[0]; Sy += r[1]; Sz += r[2];
      Mnx = fminf(Mnx, r[3]); Mny = fminf(Mny, r[4]); Mnz = fminf(Mnz, r[5]);
      Mxx = fmaxf(Mxx, r[6]); Mxy = fmaxf(Mxy, r[7]); Mxz = fmaxf(Mxz, r[8]);
    }
    float n = (float)npts;
    float cmx = Sx / n, cmy = Sy / n, cmz = Sz / n;
    float cminx = Mnx - cmx, cminy = Mny - cmy, cminz = Mnz - cmz;
    float cmaxx = Mxx - cmx, cmaxy = Mxy - cmy, cmaxz = Mxz - cmz;
    float r0 = (cmaxx - cminx) / 14.0f;
    float r1 = (cmaxy - cminy) / 14.0f;
    float r2 = (cmaxz - cminz) / 14.0f;
    float cs = 1.0f / fmaxf(fmaxf(r0, r1), r2) - 0.01f;
    cs = fminf(cs, 50.0f);
    float r3x = rand3[0], r3y = rand3[1], r3z = rand3[2];
    float mn0 = cminx * cs, mx0 = cmaxx * cs, b0 = mx0 - mn0;
    float mn1 = cminy * cs, mx1 = cmaxy * cs, b1 = mx1 - mn1;
    float mn2 = cminz * cs, mx2 = cmaxz * cs, b2 = mx2 - mn2;
    float ox = -mn0 + fmaxf(14.0f - b0 - 0.001f, 0.0f) * r3x +
               fminf(14.0f - b0 + 0.001f, 0.0f) * r3x;
    float oy = -mn1 + fmaxf(14.0f - b1 - 0.001f, 0.0f) * r3y +
               fminf(14.0f - b1 + 0.001f, 0.0f) * r3y;
    float oz = -mn2 + fmaxf(14.0f - b2 - 0.001f, 0.0f) * r3z +
               fminf(14.0f - b2 + 0.001f, 0.0f) * r3z;
    s_bcast[0] = cmx; s_bcast[1] = cmy; s_bcast[2] = cmz;
    s_bcast[3] = cs;
    s_bcast[4] = ox; s_bcast[5] = oy; s_bcast[6] = oz;
  }
  __syncthreads();
  const float cmx = s_bcast[0], cmy = s_bcast[1], cmz = s_bcast[2];
  const float cs = s_bcast[3];
  const float ox = s_bcast[4], oy = s_bcast[5], oz = s_bcast[6];

  // ---- voxel ids (reference FP op order) ----
  int vid[kPPT];
#pragma unroll
  for (int k = 0; k < kPPT; k++) {
    if (pt[k] >= 0) {
      float tx = (px[k] - cmx) * cs + ox;
      float ty = (py[k] - cmy) * cs + oy;
      float tz = (pz[k] - cmz) * cs + oz;
      int vx = min(kFS - 1, max(0, (int)floorf(tx)));
      int vy = min(kFS - 1, max(0, (int)floorf(ty)));
      int vz = min(kFS - 1, max(0, (int)floorf(tz)));
      vid[k] = (vx * kFS + vy) * kFS + vz;
    } else {
      vid[k] = -1;
    }
  }

  // ---- counting sort: counts ----
  for (int v = tid; v < kNVOX; v += kBLK) s_cnt[v] = 0;
  __syncthreads();
#pragma unroll
  for (int k = 0; k < kPPT; k++)
    if (vid[k] >= 0) atomicAdd(&s_cnt[vid[k]], 1);
  __syncthreads();

  // ---- exclusive prefix scan over s_cnt -> s_off; also fill s_rinv ----
  {
    const int base = tid * kCPT;
    int local[kCPT];
    int sum = 0;
#pragma unroll
    for (int j = 0; j < kCPT; j++) {
      int v = base + j;
      int x = (v < kNVOX) ? s_cnt[v] : 0;
      if (v < kNVOX) s_rinv[v] = (x > 0) ? (1.0f / (float)x) : 0.0f;
      local[j] = sum;
      sum += x;
    }
    int inc = sum;
#pragma unroll
    for (int o = 1; o < 64; o <<= 1) {
      int t = __shfl_up(inc, o);
      if (lane >= o) inc += t;
    }
    if (lane == 63) s_wt[wave] = inc;
    __syncthreads();
    if (tid == 0) {
      int a = 0;
      for (int w = 0; w < kW; w++) {
        int t = s_wt[w];
        s_wt[w] = a;
        a += t;
      }
    }
    __syncthreads();
    const int texcl = s_wt[wave] + inc - sum;
#pragma unroll
    for (int j = 0; j < kCPT; j++) {
      int v = base + j;
      if (v < kNVOX) s_off[v] = texcl + local[j];
    }
  }
  __syncthreads();

  // ---- scatter (s_off becomes per-voxel END); pack (vid<<20)|pid ----
#pragma unroll
  for (int k = 0; k < kPPT; k++) {
    if (vid[k] >= 0) {
      int pos = atomicAdd(&s_off[vid[k]], 1);
      s_pack[pos] = ((unsigned)vid[k] << 20) | (unsigned)pt[k];
    }
  }
  __syncthreads();

  // ---- flat-run gather: group g owns voxels STARTING in [16g, 16g+16) ----
  const int grp = tid >> 3;               // 0..127
  const int gl  = tid & 7;                // channel quad
  const size_t chOff = (size_t)gl * 4;
  float m0 = -FLT_MAX, m1 = -FLT_MAX, m2 = -FLT_MAX, m3 = -FLT_MAX;

  {
    const int p0 = grp * kGPW;
    if (p0 < npts) {
      const int p1 = min(p0 + kGPW, npts);
      const int v0 = (int)(s_pack[p0] >> 20);
      // skip head run continuing from previous window (s_off[v] = run END)
      int s = p0;
      if (p0 > 0 && (int)(s_pack[p0 - 1] >> 20) == v0) s = s_off[v0];
      // end of the run containing the window's last position
      const int vend = (int)(s_pack[p1 - 1] >> 20);
      const int pend = s_off[vend];  // if head run covers window: pend==s

      int curv = -1;
      float rin = 1.0f;
      float a0 = 0.f, a1 = 0.f, a2 = 0.f, a3 = 0.f;
      for (int base = s; base < pend; base += 8) {
        // clamped sorted positions -> ALL 8 loads unconditional & independent
        const int j0 = base + 0, j1 = min(base + 1, pend - 1),
                  j2 = min(base + 2, pend - 1), j3 = min(base + 3, pend - 1),
                  j4 = min(base + 4, pend - 1), j5 = min(base + 5, pend - 1),
                  j6 = min(base + 6, pend - 1), j7 = min(base + 7, pend - 1);
        const unsigned w0 = s_pack[j0], w1 = s_pack[j1], w2 = s_pack[j2],
                       w3 = s_pack[j3], w4 = s_pack[j4], w5 = s_pack[j5],
                       w6 = s_pack[j6], w7 = s_pack[j7];
        const float4 f0 = *reinterpret_cast<const float4*>(
            &feats[(size_t)(w0 & 0xFFFFFu) * kC + chOff]);
        const float4 f1 = *reinterpret_cast<const float4*>(
            &feats[(size_t)(w1 & 0xFFFFFu) * kC + chOff]);
        const float4 f2 = *reinterpret_cast<const float4*>(
            &feats[(size_t)(w2 & 0xFFFFFu) * kC + chOff]);
        const float4 f3 = *reinterpret_cast<const float4*>(
            &feats[(size_t)(w3 & 0xFFFFFu) * kC + chOff]);
        const float4 f4 = *reinterpret_cast<const float4*>(
            &feats[(size_t)(w4 & 0xFFFFFu) * kC + chOff]);
        const float4 f5 = *reinterpret_cast<const float4*>(
            &feats[(size_t)(w5 & 0xFFFFFu) * kC + chOff]);
        const float4 f6 = *reinterpret_cast<const float4*>(
            &feats[(size_t)(w6 & 0xFFFFFu) * kC + chOff]);
        const float4 f7 = *reinterpret_cast<const float4*>(
            &feats[(size_t)(w7 & 0xFFFFFu) * kC + chOff]);
        const int m = pend - base;
#define PG_ACC(K, WK, FK)                                                  \
        if (m > K) {                                                       \
          const int vv = (int)(WK >> 20);                                  \
          if (vv != curv) {                                                \
            if (curv >= 0) {                                               \
              m0 = fmaxf(m0, a0 * rin); m1 = fmaxf(m1, a1 * rin);          \
              m2 = fmaxf(m2, a2 * rin); m3 = fmaxf(m3, a3 * rin);          \
            }                                                              \
            curv = vv; rin = s_rinv[vv];                                   \
            a0 = FK.x; a1 = FK.y; a2 = FK.z; a3 = FK.w;                    \
          } else {                                                         \
            a0 += FK.x; a1 += FK.y; a2 += FK.z; a3 += FK.w;                \
          }                                                                \
        }
        PG_ACC(0, w0, f0) PG_ACC(1, w1, f1) PG_ACC(2, w2, f2)
        PG_ACC(3, w3, f3) PG_ACC(4, w4, f4) PG_ACC(5, w5, f5)
        PG_ACC(6, w6, f6) PG_ACC(7, w7, f7)
#undef PG_ACC
      }
      if (curv >= 0) {
        m0 = fmaxf(m0, a0 * rin); m1 = fmaxf(m1, a1 * rin);
        m2 = fmaxf(m2, a2 * rin); m3 = fmaxf(m3, a3 * rin);
      }
    }
  }

  // reduce across the 8 groups within the wave (stride 8,16,32)
#pragma unroll
  for (int o = 8; o < 64; o <<= 1) {
    m0 = fmaxf(m0, __shfl_down(m0, o));
    m1 = fmaxf(m1, __shfl_down(m1, o));
    m2 = fmaxf(m2, __shfl_down(m2, o));
    m3 = fmaxf(m3, __shfl_down(m3, o));
  }
  if (lane < 8) {
    float* r = &s_redmax[wave * kC + lane * 4];
    r[0] = m0; r[1] = m1; r[2] = m2; r[3] = m3;
  }
  __syncthreads();
  if (tid < kC) {
    float mm = s_redmax[tid];
    for (int w = 1; w < kW; w++) mm = fmaxf(mm, s_redmax[w * kC + tid]);
    s_redmax[tid] = mm;
  }
  __syncthreads();

  // ---- score ----
  if (tid == 0) {
    float acc = bias[0];
    for (int j = 0; j < kC; j++) acc += s_redmax[j] * W[j];
    out[c] = acc;
  }
}

extern "C" void kernel_launch(void* const* d_in, const int* in_sizes, int n_in,
                              void* d_out, int out_size, void* d_ws,
                              size_t ws_size, hipStream_t stream) {
  const float* feats  = (const float*)d_in[0];
  const float* coords = (const float*)d_in[1];
  const float* W      = (const float*)d_in[2];
  const float* bias   = (const float*)d_in[3];
  const float* rand3  = (const float*)d_in[4];
  const int* cidx     = (const int*)d_in[5];
  const int* coff     = (const int*)d_in[6];
  float* out          = (float*)d_out;

  int nC = in_sizes[6] - 1;
  pg_kernel<<<nC, kBLK, 0, stream>>>(feats, coords, W, bias, rand3, cidx, coff,
                                     out);
}